// Round 3
// baseline (230.943 us; speedup 1.0000x reference)
//
#include <hip/hip_runtime.h>

// Multiresolution hash encoding, MI355X. Round 3: latency-bound fix.
// - 2 threads per sample: even levels / odd levels (wave-uniform split).
//   => 8192 waves = 32 waves/CU (was 16), balanced work per half.
// - Explicit 2-level software pipeline (double-buffered PREP/CONSUME),
//   ~16 gathers in flight per wave (was ~8, serialized).
// - __launch_bounds__(256,8) targets <=64 VGPR for 8 waves/SIMD.

constexpr int      kT    = 524288;       // 2^19 rows per level
constexpr unsigned kMask = kT - 1;
constexpr int      kB    = 262144;
constexpr unsigned kP1   = 2654435761u;
constexpr unsigned kP2   = 805459861u;

typedef float f32x2 __attribute__((ext_vector_type(2)));

template <int H>  // H = 0: levels 0,2,..,14 ; H = 1: levels 1,3,..,15
__device__ __forceinline__ void run_levels(const float x0, const float x1, const float x2,
                                           const f32x2* __restrict__ tables,
                                           f32x2* __restrict__ out, const int s) {
    constexpr float kResF[16] = {16, 20, 25, 32, 40, 50, 64, 80,
                                 101, 128, 161, 203, 256, 322, 406, 512};
    f32x2 buf[2][8];   // double-buffered gather data (static idx only)
    float rr[2][3];    // fractional coords of in-flight levels

#define PREP(I)                                                                  \
    {                                                                            \
        constexpr int l = H + 2 * (I);                                           \
        const float res = kResF[l];                                              \
        const float s0 = x0 * res, s1 = x1 * res, s2 = x2 * res;                 \
        const float f0 = floorf(s0), f1 = floorf(s1), f2 = floorf(s2);           \
        rr[(I) & 1][0] = s0 - f0;                                                \
        rr[(I) & 1][1] = s1 - f1;                                                \
        rr[(I) & 1][2] = s2 - f2;                                                \
        const unsigned c0 = (unsigned)f0;                                        \
        const unsigned h1a = (unsigned)f1 * kP1, h1b = h1a + kP1;                \
        const unsigned h2a = (unsigned)f2 * kP2, h2b = h2a + kP2;                \
        const f32x2* __restrict__ tab = tables + (size_t)l * kT;                 \
        _Pragma("unroll")                                                        \
        for (int v = 0; v < 8; ++v) {                                            \
            const unsigned g0 = (v & 1) ? (c0 + 1u) : c0;                        \
            const unsigned g1 = (v & 2) ? h1b : h1a;                             \
            const unsigned g2 = (v & 4) ? h2b : h2a;                             \
            buf[(I) & 1][v] = tab[(g0 ^ g1 ^ g2) & kMask];                       \
        }                                                                        \
    }

#define CONSUME(I)                                                               \
    {                                                                            \
        const float r0 = rr[(I) & 1][0], r1 = rr[(I) & 1][1], r2 = rr[(I) & 1][2]; \
        const float w0a = 1.f - r0, w1a = 1.f - r1, w2a = 1.f - r2;              \
        float a0 = 0.f, a1 = 0.f;                                                \
        _Pragma("unroll")                                                        \
        for (int v = 0; v < 8; ++v) {                                            \
            const float w = ((v & 1) ? r0 : w0a) *                               \
                            ((v & 2) ? r1 : w1a) *                               \
                            ((v & 4) ? r2 : w2a);                                \
            a0 = fmaf(w, buf[(I) & 1][v].x, a0);                                 \
            a1 = fmaf(w, buf[(I) & 1][v].y, a1);                                 \
        }                                                                        \
        f32x2 o;                                                                 \
        o.x = a0;                                                                \
        o.y = a1;                                                                \
        __builtin_nontemporal_store(o, out + (size_t)s * 16 + (H + 2 * (I)));    \
    }

    PREP(0)
    PREP(1)
    CONSUME(0)
    PREP(2)
    CONSUME(1)
    PREP(3)
    CONSUME(2)
    PREP(4)
    CONSUME(3)
    PREP(5)
    CONSUME(4)
    PREP(6)
    CONSUME(5)
    PREP(7)
    CONSUME(6)
    CONSUME(7)
#undef PREP
#undef CONSUME
}

__global__ __launch_bounds__(256, 8) void hashenc(const float* __restrict__ x,
                                                  const f32x2* __restrict__ tables,
                                                  f32x2* __restrict__ out) {
    const int tid = threadIdx.x;
    const int s = blockIdx.x * 128 + (tid & 127);  // waves 0,1 & 2,3 cover same samples
    const float x0 = x[3 * s + 0];
    const float x1 = x[3 * s + 1];
    const float x2 = x[3 * s + 2];
    if (tid < 128) {  // wave-uniform branch (waves 0,1)
        run_levels<0>(x0, x1, x2, tables, out, s);
    } else {          // waves 2,3
        run_levels<1>(x0, x1, x2, tables, out, s);
    }
}

extern "C" void kernel_launch(void* const* d_in, const int* in_sizes, int n_in,
                              void* d_out, int out_size, void* d_ws, size_t ws_size,
                              hipStream_t stream) {
    const float*  x      = (const float*)d_in[0];
    const f32x2*  tables = (const f32x2*)d_in[1];
    f32x2*        out    = (f32x2*)d_out;
    hashenc<<<kB / 128, 256, 0, stream>>>(x, tables, out);
}

// Round 4
// 208.924 us; speedup vs baseline: 1.1054x; 1.1054x over previous
//
#include <hip/hip_runtime.h>

// Multiresolution hash encoding, MI355X. Round 4: XCD-level pinning.
// Diagnosis: kernel is L2-fill-traffic-bound (~3.2 TB/s); dur tracks hbm_bytes
// across R2/R3. Fix = cut cross-L2 duplication: each XCD (blockIdx&7, dispatch
// round-robin) owns level pair {2*xcd, 2*xcd+1}; phases ordered so each
// XCD-private 4MB L2 holds ONE ~4MB level table at a time.
// Writes: per sample each block owns 16B of the 128B output row (levels
// 2i,2i+1 adjacent -> one f32x4 nontemporal store); ~4x sector amplification
// accepted (cheaper than the 6x fetch reduction it buys).

constexpr int      kT    = 524288;       // 2^19 rows per level
constexpr unsigned kMask = kT - 1;
constexpr int      kB    = 262144;
constexpr unsigned kP1   = 2654435761u;
constexpr unsigned kP2   = 805459861u;

typedef float f32x2 __attribute__((ext_vector_type(2)));
typedef float f32x4 __attribute__((ext_vector_type(4)));

__global__ __launch_bounds__(256, 8) void hashenc(const float* __restrict__ x,
                                                  const f32x2* __restrict__ tables,
                                                  f32x4* __restrict__ out) {
    // floor(16 * b^l), b = 2^(1/3) rounding-traced (verified R2, absmax 4.8e-7)
    constexpr float kResF[16] = {16, 20, 25, 32, 40, 50, 64, 80,
                                 101, 128, 161, 203, 256, 322, 406, 512};

    const int xcd = blockIdx.x & 7;    // dispatch round-robins blocks over XCDs
    const int bi  = blockIdx.x >> 3;   // 0..255 within this XCD
    const int tid = threadIdx.x;
    const int sbase = bi * 1024 + tid; // 4 samples per thread, stride 256

    // Load coords for the 4 samples once (coalesced: 3 dwords/thread)
    float X0[4], X1[4], X2[4];
#pragma unroll
    for (int it = 0; it < 4; ++it) {
        const int s = sbase + 256 * it;
        X0[it] = x[3 * s + 0];
        X1[it] = x[3 * s + 1];
        X2[it] = x[3 * s + 2];
    }

    float acc[2][4][2];  // [phase][iter][feat] — fully static after unroll

#pragma unroll
    for (int p = 0; p < 2; ++p) {      // phase-ordered: one level at a time in L2
        const int l = 2 * xcd + p;     // wave-uniform
        const float res = kResF[l];
        const f32x2* __restrict__ tab = tables + (size_t)l * kT;
#pragma unroll
        for (int it = 0; it < 4; ++it) {
            const float s0 = X0[it] * res, s1 = X1[it] * res, s2 = X2[it] * res;
            const float f0 = floorf(s0), f1 = floorf(s1), f2 = floorf(s2);
            const float r0 = s0 - f0, r1 = s1 - f1, r2 = s2 - f2;
            const unsigned c0 = (unsigned)f0;
            const unsigned h1a = (unsigned)f1 * kP1, h1b = h1a + kP1;
            const unsigned h2a = (unsigned)f2 * kP2, h2b = h2a + kP2;
            const float w0a = 1.f - r0, w1a = 1.f - r1, w2a = 1.f - r2;
            float a0 = 0.f, a1 = 0.f;
#pragma unroll
            for (int v = 0; v < 8; ++v) {
                const unsigned g0 = (v & 1) ? (c0 + 1u) : c0;
                const unsigned g1 = (v & 2) ? h1b : h1a;
                const unsigned g2 = (v & 4) ? h2b : h2a;
                const f32x2 f = tab[(g0 ^ g1 ^ g2) & kMask];
                const float w = ((v & 1) ? r0 : w0a) *
                                ((v & 2) ? r1 : w1a) *
                                ((v & 4) ? r2 : w2a);
                a0 = fmaf(w, f.x, a0);
                a1 = fmaf(w, f.y, a1);
            }
            acc[p][it][0] = a0;
            acc[p][it][1] = a1;
        }
    }

    // Store: levels 2*xcd, 2*xcd+1 are floats [4*xcd .. 4*xcd+4) of the
    // 32-float output row -> one 16B nontemporal store per sample.
#pragma unroll
    for (int it = 0; it < 4; ++it) {
        const int s = sbase + 256 * it;
        f32x4 o;
        o.x = acc[0][it][0];
        o.y = acc[0][it][1];
        o.z = acc[1][it][0];
        o.w = acc[1][it][1];
        __builtin_nontemporal_store(o, out + (size_t)s * 8 + xcd);
    }
}

extern "C" void kernel_launch(void* const* d_in, const int* in_sizes, int n_in,
                              void* d_out, int out_size, void* d_ws, size_t ws_size,
                              hipStream_t stream) {
    const float*  x      = (const float*)d_in[0];
    const f32x2*  tables = (const f32x2*)d_in[1];
    f32x4*        out    = (f32x4*)d_out;
    hashenc<<<2048, 256, 0, stream>>>(x, tables, out);
}

// Round 5
// 171.153 us; speedup vs baseline: 1.3493x; 1.2207x over previous
//
#include <hip/hip_runtime.h>

// Multiresolution hash encoding, MI355X. Round 5: gather-request reduction.
// Diagnosis: R2/R3/R4 all ~200-230us regardless of HBM traffic (635/750/449MB)
// => vector-memory REQUEST-throughput bound (33.5M random 8B lane-gathers,
// 0.26 req/cyc/CU). Lever: dim-0 hash prime == 1, so corners (c0,c0+1) are
// XOR-adjacent table entries when c0 even -> one aligned 16B float4 holds both.
// Per level: 4 (y,z)-combos x two 16B pair-loads; for even-c0 lanes both loads
// alias the same line (2nd is an L1 hit). Expected distinct-line misses/level:
// 8 -> 6 avg. Structure otherwise = R2 (1 thread/sample, 16 levels unrolled,
// lockstep level phases, row in registers, 8x16B nt stores).

constexpr int      kT    = 524288;       // 2^19 rows per level
constexpr unsigned kMask = kT - 1;
constexpr int      kB    = 262144;
constexpr unsigned kP1   = 2654435761u;
constexpr unsigned kP2   = 805459861u;

typedef float f32x4 __attribute__((ext_vector_type(4)));

__global__ __launch_bounds__(256, 4) void hashenc(const float* __restrict__ x,
                                                  const f32x4* __restrict__ tab4base,
                                                  f32x4* __restrict__ out) {
    const int b = blockIdx.x * 256 + threadIdx.x;
    const float x0 = x[3 * b + 0];
    const float x1 = x[3 * b + 1];
    const float x2 = x[3 * b + 2];

    f32x4 o[8];  // 32-float output row, static indices only

    // floor(16 * b^l), b = 2^(1/3): rounding-traced, verified (absmax 4.8e-7)
    constexpr float kResF[16] = {16, 20, 25, 32, 40, 50, 64, 80,
                                 101, 128, 161, 203, 256, 322, 406, 512};

#pragma unroll
    for (int l = 0; l < 16; ++l) {
        const float res = kResF[l];
        const float s0 = x0 * res, s1 = x1 * res, s2 = x2 * res;
        const float f0 = floorf(s0), f1 = floorf(s1), f2 = floorf(s2);
        const float r0 = s0 - f0, r1 = s1 - f1, r2 = s2 - f2;
        const unsigned c0 = (unsigned)f0;
        const unsigned h1a = (unsigned)f1 * kP1, h1b = h1a + kP1;
        const unsigned h2a = (unsigned)f2 * kP2, h2b = h2a + kP2;
        const float w0a = 1.0f - r0, w1a = 1.0f - r1, w2a = 1.0f - r2;
        // table viewed as f32x4[T/2]: element j = entries {2j, 2j+1}
        const f32x4* __restrict__ tab4 = tab4base + (size_t)l * (kT / 2);
        float a0 = 0.0f, a1 = 0.0f;
#pragma unroll
        for (int q = 0; q < 4; ++q) {  // (y,z) corner combos
            const unsigned g = ((q & 1) ? h1b : h1a) ^ ((q & 2) ? h2b : h2a);
            const unsigned i0 = (c0 ^ g) & kMask;         // entry of corner c0
            const unsigned i1 = ((c0 + 1u) ^ g) & kMask;  // entry of corner c0+1
            const f32x4 A = tab4[i0 >> 1];  // {entry i0&~1, entry i0|1}
            const f32x4 B = tab4[i1 >> 1];  // == A's line when c0 even (L1 hit)
            const float p0x = (i0 & 1) ? A.z : A.x;
            const float p0y = (i0 & 1) ? A.w : A.y;
            const float p1x = (i1 & 1) ? B.z : B.x;
            const float p1y = (i1 & 1) ? B.w : B.y;
            const float wyz = ((q & 1) ? r1 : w1a) * ((q & 2) ? r2 : w2a);
            const float wl = wyz * w0a;  // corner c0   weight
            const float wr = wyz * r0;   // corner c0+1 weight
            a0 = fmaf(wl, p0x, fmaf(wr, p1x, a0));
            a1 = fmaf(wl, p0y, fmaf(wr, p1y, a1));
        }
        if (l & 1) { o[l >> 1].z = a0; o[l >> 1].w = a1; }
        else       { o[l >> 1].x = a0; o[l >> 1].y = a1; }
    }

    f32x4* op = out + (size_t)b * 8;
#pragma unroll
    for (int k = 0; k < 8; ++k) __builtin_nontemporal_store(o[k], op + k);
}

extern "C" void kernel_launch(void* const* d_in, const int* in_sizes, int n_in,
                              void* d_out, int out_size, void* d_ws, size_t ws_size,
                              hipStream_t stream) {
    const float*  x      = (const float*)d_in[0];
    const f32x4*  tab4   = (const f32x4*)d_in[1];
    f32x4*        out    = (f32x4*)d_out;
    hashenc<<<kB / 256, 256, 0, stream>>>(x, tab4, out);
}